// Round 11
// baseline (286.674 us; speedup 1.0000x reference)
//
#include <hip/hip_runtime.h>
#include <math.h>

#define F_IN 512
#define HC1 256   // HEADS*HID
#define HEADS 4
#define HID 64
#define NCLS 64
#define NEG_SLOPE 0.2f
#define EPS_DENOM 1e-16f

using short8 = __attribute__((ext_vector_type(8))) short;
using f32x4  = __attribute__((ext_vector_type(4))) float;

__device__ inline float wave_sum(float v) {
#pragma unroll
  for (int s = 32; s > 0; s >>= 1) v += __shfl_xor(v, s);
  return v;
}

__device__ inline unsigned short f2bf(float f) {
  unsigned int u = __float_as_uint(f);
  u = (u + 0x7FFF + ((u >> 16) & 1)) >> 16;   // RNE
  return (unsigned short)u;
}
__device__ inline float bflo(unsigned int u) { return __uint_as_float(u << 16); }
__device__ inline float bfhi(unsigned int u) { return __uint_as_float(u & 0xFFFF0000u); }

__device__ inline unsigned int cvtpk_bf16(float lo, float hi) {
  unsigned int r;
  asm("v_cvt_pk_bf16_f32 %0, %1, %2" : "=v"(r) : "v"(lo), "v"(hi));
  return r;
}

__device__ inline void async_copy16(const void* g, void* l) {
  __builtin_amdgcn_global_load_lds((const __attribute__((address_space(1))) void*)g,
                                   (__attribute__((address_space(3))) void*)l, 16, 0, 0);
}

// ---------------- prep: W1T + W2T transpose-casts + cnt zeroing (one kernel) --------

__global__ void prep_kernel(const float* __restrict__ W1, unsigned short* __restrict__ W1T,
                            const float* __restrict__ W2, unsigned short* __restrict__ W2T,
                            int* __restrict__ cnt, int n) {
  const int n1 = F_IN * HC1;     // 131072
  const int n2 = HC1 * NCLS;     // 16384
  int id = blockIdx.x * blockDim.x + threadIdx.x;
  if (id < n1) {
    int nn = id / F_IN, k = id % F_IN;
    W1T[id] = f2bf(W1[(size_t)k * HC1 + nn]);
  } else if (id < n1 + n2) {
    int j = id - n1;
    int nn = j / HC1, k = j % HC1;
    W2T[j] = f2bf(W2[(size_t)k * NCLS + nn]);
  } else if (id < n1 + n2 + n) {
    cnt[id - n1 - n2] = 0;
  }
}

// ---------------- CSR build ----------------

__global__ void hist_kernel(const int* __restrict__ dst, int E, int* __restrict__ cnt) {
  int i = blockIdx.x * blockDim.x + threadIdx.x;
  int stride = gridDim.x * blockDim.x;
  for (int e = i; e < E; e += stride) atomicAdd(&cnt[dst[e]], 1);
}

__global__ void scan_blocks_kernel(const int* __restrict__ cnt, int n,
                                   int* __restrict__ rowoff, int* __restrict__ cursor,
                                   int* __restrict__ bsum) {
  __shared__ int wpart[16];
  int b = blockIdx.x, tid = threadIdx.x;
  int i = b * 1024 + tid;
  int lane = tid & 63, wid = tid >> 6;
  int v = (i < n) ? (cnt[i] + 1) : 0;   // +1 = self loop
  int x = v;
#pragma unroll
  for (int s = 1; s < 64; s <<= 1) {
    int t = __shfl_up(x, s);
    if (lane >= s) x += t;
  }
  if (lane == 63) wpart[wid] = x;
  __syncthreads();
  if (wid == 0) {
    int p = (lane < 16) ? wpart[lane] : 0;
#pragma unroll
    for (int s = 1; s < 16; s <<= 1) {
      int t = __shfl_up(p, s);
      if (lane >= s) p += t;
    }
    if (lane < 16) wpart[lane] = p;
  }
  __syncthreads();
  int incl = x + (wid ? wpart[wid - 1] : 0);
  if (i < n) { rowoff[i + 1] = incl; cursor[i] = incl - v; }
  if (tid == 1023) bsum[b] = incl;
  if (b == 0 && tid == 0) rowoff[0] = 0;
}

// scan_add with inline partials-scan (each block scans bsum[0..nb) itself; nb<=64)
__global__ void scan_add_kernel(int n, int* __restrict__ rowoff, int* __restrict__ cursor,
                                const int* __restrict__ bsum, int nb) {
  __shared__ int sscan[64];
  int tid = threadIdx.x;
  if (tid < 64) {
    int v = (tid < nb) ? bsum[tid] : 0;
    int x = v;
#pragma unroll
    for (int s = 1; s < 64; s <<= 1) {
      int t = __shfl_up(x, s);
      if (tid >= s) x += t;
    }
    sscan[tid] = x;   // inclusive
  }
  __syncthreads();
  int off = blockIdx.x ? sscan[blockIdx.x - 1] : 0;
  int i = blockIdx.x * 1024 + tid;
  if (i < n) { rowoff[i + 1] += off; cursor[i] += off; }
}

__global__ void scatter_kernel(const int* __restrict__ src, const int* __restrict__ dst,
                               int E, int n, int* __restrict__ cursor, int* __restrict__ esrc) {
  int i = blockIdx.x * blockDim.x + threadIdx.x;
  int stride = gridDim.x * blockDim.x;
  for (int e = i; e < E + n; e += stride) {
    int s, d;
    if (e < E) { s = src[e]; d = dst[e]; } else { s = e - E; d = s; }
    int pos = atomicAdd(&cursor[d], 1);
    esrc[pos] = s;
  }
}

// ---------------- GEMM1: x(fp32)@W1 -> h1b(bf16), fused attn1 dots ----------------
// BM=64 x BN=128, 4 waves of 32x64. A staged fp32 via global_load_lds (dbuf, 16KB).
// B NOT staged: W1T is 256KB = L2-resident; fragments loaded straight to regs, so
// the per-iter barrier only drains A's 2 async loads; B latency hides under MFMA.

__global__ __launch_bounds__(256)
void gemm1_fused_kernel(const float* __restrict__ A, const unsigned short* __restrict__ BT,
                        unsigned short* __restrict__ Cb,
                        const float* __restrict__ as1, const float* __restrict__ ad1,
                        float* __restrict__ als, float* __restrict__ ald, int M) {
  constexpr int BM = 64, BN = 128, BK = 32, K = F_IN, Nn = HC1;
  __shared__ float Af[2][BM * BK];             // 8KB each (16KB total)
  const int t = threadIdx.x;
  const int lane = t & 63;
  const int w = t >> 6;                        // 0..3
  const int wrow = (w >> 1) * 32;
  const int wcol = (w & 1) * 64;
  const int row0 = blockIdx.y * BM;
  const int col0 = blockIdx.x * BN;
  const int head = (col0 + wcol) >> 6;         // wave owns one full head (64 cols)
  const int lrow = lane & 15;
  const int lk = (lane >> 4) * 8;

  auto stageA = [&](int buf, int k0) {
#pragma unroll
    for (int i = 0; i < 2; ++i) {
      int c = i * 256 + t;                     // 512 chunks: row=c>>3, slot=c&7
      int r = c >> 3, sl = c & 7;
      int grow = row0 + r; if (grow > M - 1) grow = M - 1;
      const float* g = A + (size_t)grow * K + k0 + sl * 4;
      async_copy16(g, (char*)&Af[buf][0] + (size_t)(i * 256 + w * 64) * 16);
    }
  };

  const unsigned short* bp[4];
#pragma unroll
  for (int n = 0; n < 4; ++n)
    bp[n] = BT + (size_t)(col0 + wcol + n * 16 + lrow) * K + lk;

  f32x4 acc[2][4] = {};
  stageA(0, 0);
  int cur = 0;
  for (int k0 = 0; k0 < K; k0 += BK) {
    __syncthreads();                           // A buf[cur] staged
    if (k0 + BK < K) stageA(cur ^ 1, k0 + BK);
    short8 b[4];
#pragma unroll
    for (int n = 0; n < 4; ++n) b[n] = *(const short8*)(bp[n] + k0);   // L2 hits
    short8 a[2];
#pragma unroll
    for (int m = 0; m < 2; ++m) {
      const float* base = &Af[cur][(wrow + m * 16 + lrow) * BK + lk];
      float4 f0 = *(const float4*)base;
      float4 f1 = *(const float4*)(base + 4);
      union { short8 s; uint4 u; } pk;
      pk.u.x = cvtpk_bf16(f0.x, f0.y); pk.u.y = cvtpk_bf16(f0.z, f0.w);
      pk.u.z = cvtpk_bf16(f1.x, f1.y); pk.u.w = cvtpk_bf16(f1.z, f1.w);
      a[m] = pk.s;
    }
#pragma unroll
    for (int m = 0; m < 2; ++m)
#pragma unroll
      for (int n = 0; n < 4; ++n)
        acc[m][n] = __builtin_amdgcn_mfma_f32_16x16x32_bf16(a[m], b[n], acc[m][n], 0, 0, 0);
    cur ^= 1;
  }

  // epilogue: C write + fused per-head attention dots
  float asv[4], adv[4];
#pragma unroll
  for (int n = 0; n < 4; ++n) {
    asv[n] = as1[head * 64 + n * 16 + lrow];
    adv[n] = ad1[head * 64 + n * 16 + lrow];
  }
#pragma unroll
  for (int m = 0; m < 2; ++m) {
#pragma unroll
    for (int j = 0; j < 4; ++j) {
      int r = row0 + wrow + m * 16 + (lane >> 4) * 4 + j;
      float ps = 0.f, pd = 0.f;
#pragma unroll
      for (int n = 0; n < 4; ++n) {
        float v = acc[m][n][j];
        ps += v * asv[n];
        pd += v * adv[n];
        if (r < M) Cb[(size_t)r * Nn + col0 + wcol + n * 16 + lrow] = f2bf(v);
      }
#pragma unroll
      for (int s = 1; s < 16; s <<= 1) {
        ps += __shfl_xor(ps, s);
        pd += __shfl_xor(pd, s);
      }
      if ((lane & 15) == 0 && r < M) {
        als[r * HEADS + head] = ps;
        ald[r * HEADS + head] = pd;
      }
    }
  }
}

// ---------------- GEMM2: hact(bf16)@W2 -> h2b(bf16), fused attn2 dots ----------

__global__ __launch_bounds__(256)
void gemm2_fused_kernel(const unsigned short* __restrict__ A,
                        const unsigned short* __restrict__ BT,
                        unsigned short* __restrict__ Cb,
                        const float* __restrict__ as2, const float* __restrict__ ad2,
                        float* __restrict__ als, float* __restrict__ ald, int M) {
  constexpr int BM = 128, BN = 64, BK = 32, K = HC1, Nn = NCLS;
  __shared__ unsigned short Alds[BM * BK];
  __shared__ unsigned short Blds[BN * BK];
  __shared__ float sps[BM], spd[BM];
  const int t = threadIdx.x;
  const int lane = t & 63;
  const int w = t >> 6;
  const int wr = (w >> 1) * 64;
  const int wc = (w & 1) * 32;
  const int row0 = blockIdx.x * BM;
  const int lrow = lane & 15;
  const int lk = (lane >> 4) * 8;
  if (t < BM) { sps[t] = 0.f; spd[t] = 0.f; }

  f32x4 acc[4][2] = {};
  for (int k0 = 0; k0 < K; k0 += BK) {
#pragma unroll
    for (int i = 0; i < 2; ++i) {
      int c = i * 256 + t;
      int arr = c >> 2;
      int ak = (c & 3) * 8;
      int grow = row0 + arr; if (grow > M - 1) grow = M - 1;
      const unsigned short* g = A + (size_t)grow * K + k0 + ak;
      unsigned short* l = Alds + (size_t)(i * 256 + w * 64) * 8;
      async_copy16(g, l);
    }
    {
      int c = t;
      int br = c >> 2;
      int bk = (c & 3) * 8;
      const unsigned short* g = BT + (size_t)br * K + k0 + bk;
      unsigned short* l = Blds + (size_t)(w * 64) * 8;
      async_copy16(g, l);
    }
    __syncthreads();
    short8 a[4], b[2];
#pragma unroll
    for (int m = 0; m < 4; ++m)
      a[m] = *(const short8*)&Alds[(wr + m * 16 + lrow) * BK + lk];
#pragma unroll
    for (int n = 0; n < 2; ++n)
      b[n] = *(const short8*)&Blds[(wc + n * 16 + lrow) * BK + lk];
#pragma unroll
    for (int m = 0; m < 4; ++m)
#pragma unroll
      for (int n = 0; n < 2; ++n)
        acc[m][n] = __builtin_amdgcn_mfma_f32_16x16x32_bf16(a[m], b[n], acc[m][n], 0, 0, 0);
    __syncthreads();
  }

  float asv[2], adv[2];
#pragma unroll
  for (int n = 0; n < 2; ++n) {
    asv[n] = as2[wc + n * 16 + lrow];
    adv[n] = ad2[wc + n * 16 + lrow];
  }
#pragma unroll
  for (int m = 0; m < 4; ++m) {
#pragma unroll
    for (int j = 0; j < 4; ++j) {
      int rl = wr + m * 16 + (lane >> 4) * 4 + j;
      int r = row0 + rl;
      float ps = 0.f, pd = 0.f;
#pragma unroll
      for (int n = 0; n < 2; ++n) {
        float v = acc[m][n][j];
        ps += v * asv[n];
        pd += v * adv[n];
        if (r < M) Cb[(size_t)r * Nn + wc + n * 16 + lrow] = f2bf(v);
      }
#pragma unroll
      for (int s = 1; s < 16; s <<= 1) {
        ps += __shfl_xor(ps, s);
        pd += __shfl_xor(pd, s);
      }
      if ((lane & 15) == 0) {
        atomicAdd(&sps[rl], ps);
        atomicAdd(&spd[rl], pd);
      }
    }
  }
  __syncthreads();
  if (t < BM) {
    int r = row0 + t;
    if (r < M) { als[r] = sps[t]; ald[r] = spd[t]; }
  }
}

// ---------------- aggregation (R9 versions — at the L3 random-gather roofline) ------

__global__ void agg1_kernel(const unsigned short* __restrict__ h1b,
                            const float4* __restrict__ als1, const float4* __restrict__ ald1,
                            const int* __restrict__ rowoff, const int* __restrict__ esrc,
                            const float* __restrict__ b1, unsigned short* __restrict__ hact,
                            int n) {
  __shared__ float wlds[4][256];
  __shared__ int   slds[4][64];
  int w = threadIdx.x >> 6;
  int node = blockIdx.x * 4 + w;
  if (node >= n) return;
  int lane = threadIdx.x & 63;
  int hi = lane >> 5;
  int cl = lane & 31;
  int head = cl >> 3;
  int beg = rowoff[node], end = rowoff[node + 1];
  float4 aldn = ald1[node];
  f32x4 accA = {0.f, 0.f, 0.f, 0.f};
  f32x4 accB = {0.f, 0.f, 0.f, 0.f};
  float dl0 = 0.f, dl1 = 0.f, dl2 = 0.f, dl3 = 0.f;

  for (int base = beg; base < end; base += 64) {
    int cnt = min(64, end - base);
    if (lane < cnt) {
      int s = esrc[base + lane];
      float4 av = als1[s];
      float v, w0, w1, w2, w3;
      v = av.x + aldn.x; v = fmaxf(v, NEG_SLOPE * v); w0 = __expf(v);
      v = av.y + aldn.y; v = fmaxf(v, NEG_SLOPE * v); w1 = __expf(v);
      v = av.z + aldn.z; v = fmaxf(v, NEG_SLOPE * v); w2 = __expf(v);
      v = av.w + aldn.w; v = fmaxf(v, NEG_SLOPE * v); w3 = __expf(v);
      dl0 += w0; dl1 += w1; dl2 += w2; dl3 += w3;
      slds[w][lane] = s;
      float4 wv = {w0, w1, w2, w3};
      *(float4*)&wlds[w][lane * 4] = wv;
    }

    uint4 dA[4], dB[4];
    float wA[4], wB[4];
    auto ISSUE = [&](int j0, uint4* d, float* wj) {
#pragma unroll
      for (int ii = 0; ii < 4; ++ii) {
        int e = j0 + 2 * ii + hi;
        bool val = e < cnt;
        int se = val ? e : 0;
        int ss = slds[w][se];
        wj[ii] = val ? wlds[w][se * 4 + head] : 0.f;
        d[ii] = *(const uint4*)&h1b[(size_t)ss * HC1 + cl * 8];
      }
    };
    auto CONSUME = [&](const uint4* d, const float* wj) {
#pragma unroll
      for (int ii = 0; ii < 4; ++ii) {
        float q = wj[ii];
        accA[0] += q * bflo(d[ii].x); accA[1] += q * bfhi(d[ii].x);
        accA[2] += q * bflo(d[ii].y); accA[3] += q * bfhi(d[ii].y);
        accB[0] += q * bflo(d[ii].z); accB[1] += q * bfhi(d[ii].z);
        accB[2] += q * bflo(d[ii].w); accB[3] += q * bfhi(d[ii].w);
      }
    };

    ISSUE(0, dA, wA);
    for (int j0 = 8;; j0 += 16) {
      bool hasB = j0 < cnt;
      if (hasB) ISSUE(j0, dB, wB);
      CONSUME(dA, wA);
      if (!hasB) break;
      bool hasA = (j0 + 8) < cnt;
      if (hasA) ISSUE(j0 + 8, dA, wA);
      CONSUME(dB, wB);
      if (!hasA) break;
    }
  }

#pragma unroll
  for (int k = 0; k < 4; ++k) {
    accA[k] += __shfl_xor(accA[k], 32);
    accB[k] += __shfl_xor(accB[k], 32);
  }
  float d0 = wave_sum(dl0), d1 = wave_sum(dl1);
  float d2 = wave_sum(dl2), d3 = wave_sum(dl3);
  float den = head < 2 ? (head == 0 ? d0 : d1) : (head == 2 ? d2 : d3);
  float rden = 1.f / (den + EPS_DENOM);
  if (hi == 0) {
    float4 bv0 = *(const float4*)&b1[cl * 8];
    float4 bv1 = *(const float4*)&b1[cl * 8 + 4];
    float o[8];
    o[0] = accA[0] * rden + bv0.x; o[1] = accA[1] * rden + bv0.y;
    o[2] = accA[2] * rden + bv0.z; o[3] = accA[3] * rden + bv0.w;
    o[4] = accB[0] * rden + bv1.x; o[5] = accB[1] * rden + bv1.y;
    o[6] = accB[2] * rden + bv1.z; o[7] = accB[3] * rden + bv1.w;
    ushort4 ov0, ov1;
#pragma unroll
    for (int k = 0; k < 8; ++k) o[k] = o[k] > 0.f ? o[k] : __expf(o[k]) - 1.f;  // ELU
    ov0.x = f2bf(o[0]); ov0.y = f2bf(o[1]); ov0.z = f2bf(o[2]); ov0.w = f2bf(o[3]);
    ov1.x = f2bf(o[4]); ov1.y = f2bf(o[5]); ov1.z = f2bf(o[6]); ov1.w = f2bf(o[7]);
    *(ushort4*)&hact[(size_t)node * HC1 + cl * 8] = ov0;
    *(ushort4*)&hact[(size_t)node * HC1 + cl * 8 + 4] = ov1;
  }
}

__global__ void agg2_kernel(const unsigned short* __restrict__ h2b,
                            const float* __restrict__ als2, const float* __restrict__ ald2,
                            const int* __restrict__ rowoff, const int* __restrict__ esrc,
                            const float* __restrict__ b2, float* __restrict__ out, int n) {
  __shared__ float wlds[4][64];
  __shared__ int   slds[4][64];
  int w = threadIdx.x >> 6;
  int node = blockIdx.x * 4 + w;
  if (node >= n) return;
  int lane = threadIdx.x & 63;
  int eg = lane >> 3;
  int cl = lane & 7;
  int beg = rowoff[node], end = rowoff[node + 1];
  float aldn = ald2[node];
  f32x4 accA = {0.f, 0.f, 0.f, 0.f};
  f32x4 accB = {0.f, 0.f, 0.f, 0.f};
  float dl = 0.f;
  for (int base = beg; base < end; base += 64) {
    int cnt = min(64, end - base);
    if (lane < cnt) {
      int s = esrc[base + lane];
      float v = als2[s] + aldn;
      v = fmaxf(v, NEG_SLOPE * v);
      float wl = __expf(v);
      dl += wl;
      slds[w][lane] = s;
      wlds[w][lane] = wl;
    }
    for (int j0 = 0; j0 < cnt; j0 += 32) {
      uint4 d[4]; float wj[4];
#pragma unroll
      for (int ii = 0; ii < 4; ++ii) {
        int e = j0 + ii * 8 + eg;
        bool val = e < cnt;
        int se = val ? e : 0;
        int ss = slds[w][se];
        wj[ii] = val ? wlds[w][se] : 0.f;
        d[ii] = *(const uint4*)&h2b[(size_t)ss * NCLS + cl * 8];
      }
#pragma unroll
      for (int ii = 0; ii < 4; ++ii) {
        float q = wj[ii];
        accA[0] += q * bflo(d[ii].x); accA[1] += q * bfhi(d[ii].x);
        accA[2] += q * bflo(d[ii].y); accA[3] += q * bfhi(d[ii].y);
        accB[0] += q * bflo(d[ii].z); accB[1] += q * bfhi(d[ii].z);
        accB[2] += q * bflo(d[ii].w); accB[3] += q * bfhi(d[ii].w);
      }
    }
  }
#pragma unroll
  for (int s = 8; s < 64; s <<= 1) {
#pragma unroll
    for (int k = 0; k < 4; ++k) {
      accA[k] += __shfl_xor(accA[k], s);
      accB[k] += __shfl_xor(accB[k], s);
    }
  }
  float den = wave_sum(dl);
  float rden = 1.f / (den + EPS_DENOM);
  float4 bv0 = *(const float4*)&b2[cl * 8];
  float4 bv1 = *(const float4*)&b2[cl * 8 + 4];
  float o[8];
  o[0] = accA[0] * rden + bv0.x; o[1] = accA[1] * rden + bv0.y;
  o[2] = accA[2] * rden + bv0.z; o[3] = accA[3] * rden + bv0.w;
  o[4] = accB[0] * rden + bv1.x; o[5] = accB[1] * rden + bv1.y;
  o[6] = accB[2] * rden + bv1.z; o[7] = accB[3] * rden + bv1.w;
  float mx = o[0];
#pragma unroll
  for (int k = 1; k < 8; ++k) mx = fmaxf(mx, o[k]);
#pragma unroll
  for (int s = 1; s < 8; s <<= 1) mx = fmaxf(mx, __shfl_xor(mx, s));
  float sm = 0.f;
#pragma unroll
  for (int k = 0; k < 8; ++k) sm += __expf(o[k] - mx);
#pragma unroll
  for (int s = 1; s < 8; s <<= 1) sm += __shfl_xor(sm, s);
  float ls = mx + __logf(sm);
  if (lane < 8) {
    float4 q0 = {o[0] - ls, o[1] - ls, o[2] - ls, o[3] - ls};
    float4 q1 = {o[4] - ls, o[5] - ls, o[6] - ls, o[7] - ls};
    *(float4*)&out[(size_t)node * NCLS + cl * 8] = q0;
    *(float4*)&out[(size_t)node * NCLS + cl * 8 + 4] = q1;
  }
}

// ---------------- launch ----------------

extern "C" void kernel_launch(void* const* d_in, const int* in_sizes, int n_in,
                              void* d_out, int out_size, void* d_ws, size_t ws_size,
                              hipStream_t stream) {
  const float* x      = (const float*)d_in[0];
  const int*   eidx   = (const int*)d_in[1];
  const float* W1     = (const float*)d_in[2];
  const float* a_src1 = (const float*)d_in[3];
  const float* a_dst1 = (const float*)d_in[4];
  const float* b1     = (const float*)d_in[5];
  const float* W2     = (const float*)d_in[6];
  const float* a_src2 = (const float*)d_in[7];
  const float* a_dst2 = (const float*)d_in[8];
  const float* b2     = (const float*)d_in[9];
  float* out = (float*)d_out;

  const int Nn = in_sizes[0] / F_IN;   // 50000
  const int E  = in_sizes[1] / 2;      // 800000
  const int* esrc_in = eidx;
  const int* edst_in = eidx + E;

  char* ws = (char*)d_ws;
  size_t off = 0;
  auto alloc = [&](size_t bytes) -> void* {
    void* p = ws + off;
    off += (bytes + 255) & ~(size_t)255;
    return p;
  };
  unsigned short* h1b    = (unsigned short*)alloc((size_t)Nn * HC1 * sizeof(short));
  unsigned short* hact   = (unsigned short*)alloc((size_t)Nn * HC1 * sizeof(short));
  unsigned short* h2b    = (unsigned short*)alloc((size_t)Nn * NCLS * sizeof(short));
  unsigned short* W1T    = (unsigned short*)alloc((size_t)F_IN * HC1 * sizeof(short));
  unsigned short* W2T    = (unsigned short*)alloc((size_t)HC1 * NCLS * sizeof(short));
  float*          als1   = (float*)alloc((size_t)Nn * HEADS * sizeof(float));
  float*          ald1   = (float*)alloc((size_t)Nn * HEADS * sizeof(float));
  float*          als2   = (float*)alloc((size_t)Nn * sizeof(float));
  float*          ald2   = (float*)alloc((size_t)Nn * sizeof(float));
  int*            cnt    = (int*)alloc((size_t)Nn * sizeof(int));
  int*            rowoff = (int*)alloc((size_t)(Nn + 1) * sizeof(int));
  int*            cursor = (int*)alloc((size_t)Nn * sizeof(int));
  int*            bsum   = (int*)alloc(256 * sizeof(int));
  int*            esrc   = (int*)alloc((size_t)(E + Nn) * sizeof(int));

  const int nscan = (Nn + 1023) / 1024;   // 49 (<=64)

  // prep: both weight transposes + cnt zeroing
  {
    int total = F_IN * HC1 + HC1 * NCLS + Nn;
    prep_kernel<<<(total + 255) / 256, 256, 0, stream>>>(W1, W1T, W2, W2T, cnt, Nn);
  }
  hist_kernel<<<(E + 255) / 256, 256, 0, stream>>>(edst_in, E, cnt);
  scan_blocks_kernel<<<nscan, 1024, 0, stream>>>(cnt, Nn, rowoff, cursor, bsum);
  scan_add_kernel<<<nscan, 1024, 0, stream>>>(Nn, rowoff, cursor, bsum, nscan);
  scatter_kernel<<<(E + Nn + 255) / 256, 256, 0, stream>>>(esrc_in, edst_in, E, Nn, cursor, esrc);

  // layer 1: GEMM (B-from-L2) + fused attn1 logits, then agg1
  {
    dim3 g(HC1 / 128, (Nn + 63) / 64);
    gemm1_fused_kernel<<<g, 256, 0, stream>>>(x, W1T, h1b, a_src1, a_dst1,
                                              als1, ald1, Nn);
    int ablocks = (Nn + 3) / 4;
    agg1_kernel<<<ablocks, 256, 0, stream>>>(h1b, (const float4*)als1, (const float4*)ald1,
                                             rowoff, esrc, b1, hact, Nn);
  }

  // layer 2: GEMM + fused attn2 logits, then agg2
  {
    int blocks = (Nn + 127) / 128;
    gemm2_fused_kernel<<<blocks, 256, 0, stream>>>(hact, W2T, h2b, a_src2, a_dst2,
                                                   als2, ald2, Nn);
    int ablocks = (Nn + 3) / 4;
    agg2_kernel<<<ablocks, 256, 0, stream>>>(h2b, als2, ald2, rowoff, esrc, b2, out, Nn);
  }
}

// Round 13
// 244.035 us; speedup vs baseline: 1.1747x; 1.1747x over previous
//
#include <hip/hip_runtime.h>
#include <math.h>

#define F_IN 512
#define HC1 256   // HEADS*HID
#define HEADS 4
#define HID 64
#define NCLS 64
#define NEG_SLOPE 0.2f
#define EPS_DENOM 1e-16f

using short8 = __attribute__((ext_vector_type(8))) short;
using f32x4  = __attribute__((ext_vector_type(4))) float;

__device__ inline float wave_sum(float v) {
#pragma unroll
  for (int s = 32; s > 0; s >>= 1) v += __shfl_xor(v, s);
  return v;
}

__device__ inline unsigned short f2bf(float f) {
  unsigned int u = __float_as_uint(f);
  u = (u + 0x7FFF + ((u >> 16) & 1)) >> 16;   // RNE
  return (unsigned short)u;
}
__device__ inline float bflo(unsigned int u) { return __uint_as_float(u << 16); }
__device__ inline float bfhi(unsigned int u) { return __uint_as_float(u & 0xFFFF0000u); }

__device__ inline unsigned int cvtpk_bf16(float lo, float hi) {
  unsigned int r;
  asm("v_cvt_pk_bf16_f32 %0, %1, %2" : "=v"(r) : "v"(lo), "v"(hi));
  return r;
}

// ---- fp8 e4m3 (OCP) encode/decode ----
__device__ inline unsigned char f2fp8(float f) {
#if __has_builtin(__builtin_amdgcn_cvt_pk_fp8_f32)
  return (unsigned char)(__builtin_amdgcn_cvt_pk_fp8_f32(f, f, 0, false) & 0xFF);
#else
  unsigned u = __float_as_uint(f);
  unsigned s = (u >> 24) & 0x80;
  float af = fabsf(f);
  if (af > 448.f) return (unsigned char)(s | 0x7E);
  if (af < 0.0009765625f) return (unsigned char)s;
  if (af < 0.015625f) {             // denorm: m = round(af * 512)
    int m = (int)(af * 512.f + 0.5f);
    return (unsigned char)(s | m);
  }
  unsigned au = u & 0x7FFFFFFF;
  unsigned r = au + 0x0007FFFF + ((au >> 20) & 1);   // RNE at bit 20
  int e = (int)(r >> 23) - 120;
  int m = (r >> 20) & 7;
  if (e > 15) { e = 15; m = 6; }
  return (unsigned char)(s | (e << 3) | m);
#endif
}

template <bool HI>
__device__ inline void fp8x2_dec(unsigned int u, float& a, float& b) {
#if __has_builtin(__builtin_amdgcn_cvt_pk_f32_fp8)
  auto r = __builtin_amdgcn_cvt_pk_f32_fp8((int)u, HI);   // HI is a constant
  a = r[0]; b = r[1];
#else
  unsigned w = HI ? (u >> 16) : u;
  auto dec1 = [](unsigned v) -> float {
    unsigned sg = v >> 7, e = (v >> 3) & 15, m = v & 7;
    float mag = e ? __uint_as_float(((e + 120u) << 23) | (m << 20))
                  : (float)m * 0.001953125f;
    return sg ? -mag : mag;
  };
  a = dec1(w & 0xFF); b = dec1((w >> 8) & 0xFF);
#endif
}

__device__ inline void async_copy16(const void* g, void* l) {
  __builtin_amdgcn_global_load_lds((const __attribute__((address_space(1))) void*)g,
                                   (__attribute__((address_space(3))) void*)l, 16, 0, 0);
}

// ---------------- prep: W1T + W2T transpose-casts + cnt zeroing (one kernel) --------

__global__ void prep_kernel(const float* __restrict__ W1, unsigned short* __restrict__ W1T,
                            const float* __restrict__ W2, unsigned short* __restrict__ W2T,
                            int* __restrict__ cnt, int n) {
  const int n1 = F_IN * HC1;     // 131072
  const int n2 = HC1 * NCLS;     // 16384
  int id = blockIdx.x * blockDim.x + threadIdx.x;
  if (id < n1) {
    int nn = id / F_IN, k = id % F_IN;
    W1T[id] = f2bf(W1[(size_t)k * HC1 + nn]);
  } else if (id < n1 + n2) {
    int j = id - n1;
    int nn = j / HC1, k = j % HC1;
    W2T[j] = f2bf(W2[(size_t)k * NCLS + nn]);
  } else if (id < n1 + n2 + n) {
    cnt[id - n1 - n2] = 0;
  }
}

// ---------------- CSR build ----------------

__global__ void hist_kernel(const int* __restrict__ dst, int E, int* __restrict__ cnt) {
  int i = blockIdx.x * blockDim.x + threadIdx.x;
  int stride = gridDim.x * blockDim.x;
  for (int e = i; e < E; e += stride) atomicAdd(&cnt[dst[e]], 1);
}

__global__ void scan_blocks_kernel(const int* __restrict__ cnt, int n,
                                   int* __restrict__ rowoff, int* __restrict__ cursor,
                                   int* __restrict__ bsum) {
  __shared__ int wpart[16];
  int b = blockIdx.x, tid = threadIdx.x;
  int i = b * 1024 + tid;
  int lane = tid & 63, wid = tid >> 6;
  int v = (i < n) ? (cnt[i] + 1) : 0;   // +1 = self loop
  int x = v;
#pragma unroll
  for (int s = 1; s < 64; s <<= 1) {
    int t = __shfl_up(x, s);
    if (lane >= s) x += t;
  }
  if (lane == 63) wpart[wid] = x;
  __syncthreads();
  if (wid == 0) {
    int p = (lane < 16) ? wpart[lane] : 0;
#pragma unroll
    for (int s = 1; s < 16; s <<= 1) {
      int t = __shfl_up(p, s);
      if (lane >= s) p += t;
    }
    if (lane < 16) wpart[lane] = p;
  }
  __syncthreads();
  int incl = x + (wid ? wpart[wid - 1] : 0);
  if (i < n) { rowoff[i + 1] = incl; cursor[i] = incl - v; }
  if (tid == 1023) bsum[b] = incl;
  if (b == 0 && tid == 0) rowoff[0] = 0;
}

__global__ void scan_add_kernel(int n, int* __restrict__ rowoff, int* __restrict__ cursor,
                                const int* __restrict__ bsum, int nb) {
  __shared__ int sscan[64];
  int tid = threadIdx.x;
  if (tid < 64) {
    int v = (tid < nb) ? bsum[tid] : 0;
    int x = v;
#pragma unroll
    for (int s = 1; s < 64; s <<= 1) {
      int t = __shfl_up(x, s);
      if (tid >= s) x += t;
    }
    sscan[tid] = x;   // inclusive
  }
  __syncthreads();
  int off = blockIdx.x ? sscan[blockIdx.x - 1] : 0;
  int i = blockIdx.x * 1024 + tid;
  if (i < n) { rowoff[i + 1] += off; cursor[i] += off; }
}

__global__ void scatter_kernel(const int* __restrict__ src, const int* __restrict__ dst,
                               int E, int n, int* __restrict__ cursor, int* __restrict__ esrc) {
  int i = blockIdx.x * blockDim.x + threadIdx.x;
  int stride = gridDim.x * blockDim.x;
  for (int e = i; e < E + n; e += stride) {
    int s, d;
    if (e < E) { s = src[e]; d = dst[e]; } else { s = e - E; d = s; }
    int pos = atomicAdd(&cursor[d], 1);
    esrc[pos] = s;
  }
}

// ---------------- GEMM1 (R9 structure): x(fp32)@W1 -> h1 fp8, fused attn1 dots ------
// Logits computed from f32 accumulators (exact); only the gathered features are fp8.

__global__ __launch_bounds__(256)
void gemm1_fused_kernel(const float* __restrict__ A, const unsigned short* __restrict__ BT,
                        unsigned char* __restrict__ Cf8,
                        const float* __restrict__ as1, const float* __restrict__ ad1,
                        float* __restrict__ als, float* __restrict__ ald, int M) {
  constexpr int BM = 64, BN = 128, BK = 32, K = F_IN, Nn = HC1;
  __shared__ float          Af[2][BM * BK];    // 8KB each
  __shared__ unsigned short Bh[2][BN * BK];    // 8KB each  (32KB total)
  const int t = threadIdx.x;
  const int lane = t & 63;
  const int w = t >> 6;                        // 0..3
  const int wrow = (w >> 1) * 32;
  const int wcol = (w & 1) * 64;
  const int row0 = blockIdx.y * BM;
  const int col0 = blockIdx.x * BN;
  const int head = (col0 + wcol) >> 6;         // wave owns one full head (64 cols)
  const int lrow = lane & 15;
  const int lk = (lane >> 4) * 8;

  auto stageA = [&](int buf, int k0) {
#pragma unroll
    for (int i = 0; i < 2; ++i) {
      int c = i * 256 + t;                     // 512 chunks: row=c>>3, slot=c&7
      int r = c >> 3, sl = c & 7;
      int grow = row0 + r; if (grow > M - 1) grow = M - 1;
      const float* g = A + (size_t)grow * K + k0 + sl * 4;
      async_copy16(g, (char*)&Af[buf][0] + (size_t)(i * 256 + w * 64) * 16);
    }
  };
  auto stageB = [&](int buf, int k0) {
#pragma unroll
    for (int i = 0; i < 2; ++i) {
      int c = i * 256 + t;                     // 512 chunks: row=c>>2, slot=c&3
      int r = c >> 2, sl = c & 3;
      const unsigned short* g = BT + (size_t)(col0 + r) * K + k0 + sl * 8;
      async_copy16(g, (char*)&Bh[buf][0] + (size_t)(i * 256 + w * 64) * 16);
    }
  };

  f32x4 acc[2][4] = {};
  stageA(0, 0); stageB(0, 0);
  int cur = 0;
  for (int k0 = 0; k0 < K; k0 += BK) {
    __syncthreads();                           // buf[cur] staged
    if (k0 + BK < K) { stageA(cur ^ 1, k0 + BK); stageB(cur ^ 1, k0 + BK); }
    short8 a[2], b[4];
#pragma unroll
    for (int m = 0; m < 2; ++m) {
      const float* base = &Af[cur][(wrow + m * 16 + lrow) * BK + lk];
      float4 f0 = *(const float4*)base;
      float4 f1 = *(const float4*)(base + 4);
      union { short8 s; uint4 u; } pk;
      pk.u.x = cvtpk_bf16(f0.x, f0.y); pk.u.y = cvtpk_bf16(f0.z, f0.w);
      pk.u.z = cvtpk_bf16(f1.x, f1.y); pk.u.w = cvtpk_bf16(f1.z, f1.w);
      a[m] = pk.s;
    }
#pragma unroll
    for (int n = 0; n < 4; ++n)
      b[n] = *(const short8*)&Bh[cur][(wcol + n * 16 + lrow) * BK + lk];
#pragma unroll
    for (int m = 0; m < 2; ++m)
#pragma unroll
      for (int n = 0; n < 4; ++n)
        acc[m][n] = __builtin_amdgcn_mfma_f32_16x16x32_bf16(a[m], b[n], acc[m][n], 0, 0, 0);
    cur ^= 1;
  }

  // epilogue: fp8 C write + fused per-head attention dots (from f32 acc)
  float asv[4], adv[4];
#pragma unroll
  for (int n = 0; n < 4; ++n) {
    asv[n] = as1[head * 64 + n * 16 + lrow];
    adv[n] = ad1[head * 64 + n * 16 + lrow];
  }
#pragma unroll
  for (int m = 0; m < 2; ++m) {
#pragma unroll
    for (int j = 0; j < 4; ++j) {
      int r = row0 + wrow + m * 16 + (lane >> 4) * 4 + j;
      float ps = 0.f, pd = 0.f;
#pragma unroll
      for (int n = 0; n < 4; ++n) {
        float v = acc[m][n][j];
        ps += v * asv[n];
        pd += v * adv[n];
        if (r < M) Cf8[(size_t)r * Nn + col0 + wcol + n * 16 + lrow] = f2fp8(v);
      }
#pragma unroll
      for (int s = 1; s < 16; s <<= 1) {
        ps += __shfl_xor(ps, s);
        pd += __shfl_xor(pd, s);
      }
      if ((lane & 15) == 0 && r < M) {
        als[r * HEADS + head] = ps;
        ald[r * HEADS + head] = pd;
      }
    }
  }
}

// ---------------- GEMM2: hact(bf16)@W2 -> h2b(bf16), fused attn2 dots ----------

__global__ __launch_bounds__(256)
void gemm2_fused_kernel(const unsigned short* __restrict__ A,
                        const unsigned short* __restrict__ BT,
                        unsigned short* __restrict__ Cb,
                        const float* __restrict__ as2, const float* __restrict__ ad2,
                        float* __restrict__ als, float* __restrict__ ald, int M) {
  constexpr int BM = 128, BN = 64, BK = 32, K = HC1, Nn = NCLS;
  __shared__ unsigned short Alds[BM * BK];
  __shared__ unsigned short Blds[BN * BK];
  __shared__ float sps[BM], spd[BM];
  const int t = threadIdx.x;
  const int lane = t & 63;
  const int w = t >> 6;
  const int wr = (w >> 1) * 64;
  const int wc = (w & 1) * 32;
  const int row0 = blockIdx.x * BM;
  const int lrow = lane & 15;
  const int lk = (lane >> 4) * 8;
  if (t < BM) { sps[t] = 0.f; spd[t] = 0.f; }

  f32x4 acc[4][2] = {};
  for (int k0 = 0; k0 < K; k0 += BK) {
#pragma unroll
    for (int i = 0; i < 2; ++i) {
      int c = i * 256 + t;
      int arr = c >> 2;
      int ak = (c & 3) * 8;
      int grow = row0 + arr; if (grow > M - 1) grow = M - 1;
      const unsigned short* g = A + (size_t)grow * K + k0 + ak;
      unsigned short* l = Alds + (size_t)(i * 256 + w * 64) * 8;
      async_copy16(g, l);
    }
    {
      int c = t;
      int br = c >> 2;
      int bk = (c & 3) * 8;
      const unsigned short* g = BT + (size_t)br * K + k0 + bk;
      unsigned short* l = Blds + (size_t)(w * 64) * 8;
      async_copy16(g, l);
    }
    __syncthreads();
    short8 a[4], b[2];
#pragma unroll
    for (int m = 0; m < 4; ++m)
      a[m] = *(const short8*)&Alds[(wr + m * 16 + lrow) * BK + lk];
#pragma unroll
    for (int n = 0; n < 2; ++n)
      b[n] = *(const short8*)&Blds[(wc + n * 16 + lrow) * BK + lk];
#pragma unroll
    for (int m = 0; m < 4; ++m)
#pragma unroll
      for (int n = 0; n < 2; ++n)
        acc[m][n] = __builtin_amdgcn_mfma_f32_16x16x32_bf16(a[m], b[n], acc[m][n], 0, 0, 0);
    __syncthreads();
  }

  float asv[2], adv[2];
#pragma unroll
  for (int n = 0; n < 2; ++n) {
    asv[n] = as2[wc + n * 16 + lrow];
    adv[n] = ad2[wc + n * 16 + lrow];
  }
#pragma unroll
  for (int m = 0; m < 4; ++m) {
#pragma unroll
    for (int j = 0; j < 4; ++j) {
      int rl = wr + m * 16 + (lane >> 4) * 4 + j;
      int r = row0 + rl;
      float ps = 0.f, pd = 0.f;
#pragma unroll
      for (int n = 0; n < 2; ++n) {
        float v = acc[m][n][j];
        ps += v * asv[n];
        pd += v * adv[n];
        if (r < M) Cb[(size_t)r * Nn + wc + n * 16 + lrow] = f2bf(v);
      }
#pragma unroll
      for (int s = 1; s < 16; s <<= 1) {
        ps += __shfl_xor(ps, s);
        pd += __shfl_xor(pd, s);
      }
      if ((lane & 15) == 0) {
        atomicAdd(&sps[rl], ps);
        atomicAdd(&spd[rl], pd);
      }
    }
  }
  __syncthreads();
  if (t < BM) {
    int r = row0 + t;
    if (r < M) { als[r] = sps[t]; ald[r] = spd[t]; }
  }
}

// ---------------- aggregation ----------------
// agg1: fp8 feature gather (halves the per-XCD L2 compulsory fill: 207 -> ~104 MB).

__global__ void agg1_kernel(const unsigned char* __restrict__ h1f8,
                            const float4* __restrict__ als1, const float4* __restrict__ ald1,
                            const int* __restrict__ rowoff, const int* __restrict__ esrc,
                            const float* __restrict__ b1, unsigned short* __restrict__ hact,
                            int n) {
  __shared__ float wlds[4][256];
  __shared__ int   slds[4][64];
  int w = threadIdx.x >> 6;
  int node = blockIdx.x * 4 + w;
  if (node >= n) return;
  int lane = threadIdx.x & 63;
  int hi = lane >> 5;        // which of the 2 edges covered by one instruction
  int cl = lane & 31;        // channels cl*8 .. cl*8+7
  int head = cl >> 3;
  int beg = rowoff[node], end = rowoff[node + 1];
  float4 aldn = ald1[node];
  f32x4 accA = {0.f, 0.f, 0.f, 0.f};
  f32x4 accB = {0.f, 0.f, 0.f, 0.f};
  float dl0 = 0.f, dl1 = 0.f, dl2 = 0.f, dl3 = 0.f;

  for (int base = beg; base < end; base += 64) {
    int cnt = min(64, end - base);
    if (lane < cnt) {
      int s = esrc[base + lane];
      float4 av = als1[s];
      float v, w0, w1, w2, w3;
      v = av.x + aldn.x; v = fmaxf(v, NEG_SLOPE * v); w0 = __expf(v);
      v = av.y + aldn.y; v = fmaxf(v, NEG_SLOPE * v); w1 = __expf(v);
      v = av.z + aldn.z; v = fmaxf(v, NEG_SLOPE * v); w2 = __expf(v);
      v = av.w + aldn.w; v = fmaxf(v, NEG_SLOPE * v); w3 = __expf(v);
      dl0 += w0; dl1 += w1; dl2 += w2; dl3 += w3;
      slds[w][lane] = s;
      float4 wv = {w0, w1, w2, w3};
      *(float4*)&wlds[w][lane * 4] = wv;
    }

    uint2 dA[4], dB[4];
    float wA[4], wB[4];
    auto ISSUE = [&](int j0, uint2* d, float* wj) {
#pragma unroll
      for (int ii = 0; ii < 4; ++ii) {
        int e = j0 + 2 * ii + hi;
        bool val = e < cnt;
        int se = val ? e : 0;
        int ss = slds[w][se];
        wj[ii] = val ? wlds[w][se * 4 + head] : 0.f;
        d[ii] = *(const uint2*)&h1f8[(size_t)ss * HC1 + cl * 8];
      }
    };
    auto CONSUME = [&](const uint2* d, const float* wj) {
#pragma unroll
      for (int ii = 0; ii < 4; ++ii) {
        float q = wj[ii];
        float a0, a1, a2, a3, b0, b1, b2, b3;
        fp8x2_dec<false>(d[ii].x, a0, a1);
        fp8x2_dec<true >(d[ii].x, a2, a3);
        fp8x2_dec<false>(d[ii].y, b0, b1);
        fp8x2_dec<true >(d[ii].y, b2, b3);
        accA[0] += q * a0; accA[1] += q * a1; accA[2] += q * a2; accA[3] += q * a3;
        accB[0] += q * b0; accB[1] += q * b1; accB[2] += q * b2; accB[3] += q * b3;
      }
    };

    ISSUE(0, dA, wA);
    for (int j0 = 8;; j0 += 16) {
      bool hasB = j0 < cnt;
      if (hasB) ISSUE(j0, dB, wB);
      CONSUME(dA, wA);
      if (!hasB) break;
      bool hasA = (j0 + 8) < cnt;
      if (hasA) ISSUE(j0 + 8, dA, wA);
      CONSUME(dB, wB);
      if (!hasA) break;
    }
  }

#pragma unroll
  for (int k = 0; k < 4; ++k) {
    accA[k] += __shfl_xor(accA[k], 32);
    accB[k] += __shfl_xor(accB[k], 32);
  }
  float d0 = wave_sum(dl0), d1 = wave_sum(dl1);
  float d2 = wave_sum(dl2), d3 = wave_sum(dl3);
  float den = head < 2 ? (head == 0 ? d0 : d1) : (head == 2 ? d2 : d3);
  float rden = 1.f / (den + EPS_DENOM);
  if (hi == 0) {
    float4 bv0 = *(const float4*)&b1[cl * 8];
    float4 bv1 = *(const float4*)&b1[cl * 8 + 4];
    float o[8];
    o[0] = accA[0] * rden + bv0.x; o[1] = accA[1] * rden + bv0.y;
    o[2] = accA[2] * rden + bv0.z; o[3] = accA[3] * rden + bv0.w;
    o[4] = accB[0] * rden + bv1.x; o[5] = accB[1] * rden + bv1.y;
    o[6] = accB[2] * rden + bv1.z; o[7] = accB[3] * rden + bv1.w;
    ushort4 ov0, ov1;
#pragma unroll
    for (int k = 0; k < 8; ++k) o[k] = o[k] > 0.f ? o[k] : __expf(o[k]) - 1.f;  // ELU
    ov0.x = f2bf(o[0]); ov0.y = f2bf(o[1]); ov0.z = f2bf(o[2]); ov0.w = f2bf(o[3]);
    ov1.x = f2bf(o[4]); ov1.y = f2bf(o[5]); ov1.z = f2bf(o[6]); ov1.w = f2bf(o[7]);
    *(ushort4*)&hact[(size_t)node * HC1 + cl * 8] = ov0;
    *(ushort4*)&hact[(size_t)node * HC1 + cl * 8 + 4] = ov1;
  }
}

__global__ void agg2_kernel(const unsigned short* __restrict__ h2b,
                            const float* __restrict__ als2, const float* __restrict__ ald2,
                            const int* __restrict__ rowoff, const int* __restrict__ esrc,
                            const float* __restrict__ b2, float* __restrict__ out, int n) {
  __shared__ float wlds[4][64];
  __shared__ int   slds[4][64];
  int w = threadIdx.x >> 6;
  int node = blockIdx.x * 4 + w;
  if (node >= n) return;
  int lane = threadIdx.x & 63;
  int eg = lane >> 3;
  int cl = lane & 7;
  int beg = rowoff[node], end = rowoff[node + 1];
  float aldn = ald2[node];
  f32x4 accA = {0.f, 0.f, 0.f, 0.f};
  f32x4 accB = {0.f, 0.f, 0.f, 0.f};
  float dl = 0.f;
  for (int base = beg; base < end; base += 64) {
    int cnt = min(64, end - base);
    if (lane < cnt) {
      int s = esrc[base + lane];
      float v = als2[s] + aldn;
      v = fmaxf(v, NEG_SLOPE * v);
      float wl = __expf(v);
      dl += wl;
      slds[w][lane] = s;
      wlds[w][lane] = wl;
    }
    for (int j0 = 0; j0 < cnt; j0 += 32) {
      uint4 d[4]; float wj[4];
#pragma unroll
      for (int ii = 0; ii < 4; ++ii) {
        int e = j0 + ii * 8 + eg;
        bool val = e < cnt;
        int se = val ? e : 0;
        int ss = slds[w][se];
        wj[ii] = val ? wlds[w][se] : 0.f;
        d[ii] = *(const uint4*)&h2b[(size_t)ss * NCLS + cl * 8];
      }
#pragma unroll
      for (int ii = 0; ii < 4; ++ii) {
        float q = wj[ii];
        accA[0] += q * bflo(d[ii].x); accA[1] += q * bfhi(d[ii].x);
        accA[2] += q * bflo(d[ii].y); accA[3] += q * bfhi(d[ii].y);
        accB[0] += q * bflo(d[ii].z); accB[1] += q * bfhi(d[ii].z);
        accB[2] += q * bflo(d[ii].w); accB[3] += q * bfhi(d[ii].w);
      }
    }
  }
#pragma unroll
  for (int s = 8; s < 64; s <<= 1) {
#pragma unroll
    for (int k = 0; k < 4; ++k) {
      accA[k] += __shfl_xor(accA[k], s);
      accB[k] += __shfl_xor(accB[k], s);
    }
  }
  float den = wave_sum(dl);
  float rden = 1.f / (den + EPS_DENOM);
  float4 bv0 = *(const float4*)&b2[cl * 8];
  float4 bv1 = *(const float4*)&b2[cl * 8 + 4];
  float o[8];
  o[0] = accA[0] * rden + bv0.x; o[1] = accA[1] * rden + bv0.y;
  o[2] = accA[2] * rden + bv0.z; o[3] = accA[3] * rden + bv0.w;
  o[4] = accB[0] * rden + bv1.x; o[5] = accB[1] * rden + bv1.y;
  o[6] = accB[2] * rden + bv1.z; o[7] = accB[3] * rden + bv1.w;
  float mx = o[0];
#pragma unroll
  for (int k = 1; k < 8; ++k) mx = fmaxf(mx, o[k]);
#pragma unroll
  for (int s = 1; s < 8; s <<= 1) mx = fmaxf(mx, __shfl_xor(mx, s));
  float sm = 0.f;
#pragma unroll
  for (int k = 0; k < 8; ++k) sm += __expf(o[k] - mx);
#pragma unroll
  for (int s = 1; s < 8; s <<= 1) sm += __shfl_xor(sm, s);
  float ls = mx + __logf(sm);
  if (lane < 8) {
    float4 q0 = {o[0] - ls, o[1] - ls, o[2] - ls, o[3] - ls};
    float4 q1 = {o[4] - ls, o[5] - ls, o[6] - ls, o[7] - ls};
    *(float4*)&out[(size_t)node * NCLS + cl * 8] = q0;
    *(float4*)&out[(size_t)node * NCLS + cl * 8 + 4] = q1;
  }
}

// ---------------- launch ----------------

extern "C" void kernel_launch(void* const* d_in, const int* in_sizes, int n_in,
                              void* d_out, int out_size, void* d_ws, size_t ws_size,
                              hipStream_t stream) {
  const float* x      = (const float*)d_in[0];
  const int*   eidx   = (const int*)d_in[1];
  const float* W1     = (const float*)d_in[2];
  const float* a_src1 = (const float*)d_in[3];
  const float* a_dst1 = (const float*)d_in[4];
  const float* b1     = (const float*)d_in[5];
  const float* W2     = (const float*)d_in[6];
  const float* a_src2 = (const float*)d_in[7];
  const float* a_dst2 = (const float*)d_in[8];
  const float* b2     = (const float*)d_in[9];
  float* out = (float*)d_out;

  const int Nn = in_sizes[0] / F_IN;   // 50000
  const int E  = in_sizes[1] / 2;      // 800000
  const int* esrc_in = eidx;
  const int* edst_in = eidx + E;

  char* ws = (char*)d_ws;
  size_t off = 0;
  auto alloc = [&](size_t bytes) -> void* {
    void* p = ws + off;
    off += (bytes + 255) & ~(size_t)255;
    return p;
  };
  unsigned char*  h1f8   = (unsigned char*)alloc((size_t)Nn * HC1);
  unsigned short* hact   = (unsigned short*)alloc((size_t)Nn * HC1 * sizeof(short));
  unsigned short* h2b    = (unsigned short*)alloc((size_t)Nn * NCLS * sizeof(short));
  unsigned short* W1T    = (unsigned short*)alloc((size_t)F_IN * HC1 * sizeof(short));
  unsigned short* W2T    = (unsigned short*)alloc((size_t)HC1 * NCLS * sizeof(short));
  float*          als1   = (float*)alloc((size_t)Nn * HEADS * sizeof(float));
  float*          ald1   = (float*)alloc((size_t)Nn * HEADS * sizeof(float));
  float*          als2   = (float*)alloc((size_t)Nn * sizeof(float));
  float*          ald2   = (float*)alloc((size_t)Nn * sizeof(float));
  int*            cnt    = (int*)alloc((size_t)Nn * sizeof(int));
  int*            rowoff = (int*)alloc((size_t)(Nn + 1) * sizeof(int));
  int*            cursor = (int*)alloc((size_t)Nn * sizeof(int));
  int*            bsum   = (int*)alloc(256 * sizeof(int));
  int*            esrc   = (int*)alloc((size_t)(E + Nn) * sizeof(int));

  const int nscan = (Nn + 1023) / 1024;   // 49 (<=64)

  {
    int total = F_IN * HC1 + HC1 * NCLS + Nn;
    prep_kernel<<<(total + 255) / 256, 256, 0, stream>>>(W1, W1T, W2, W2T, cnt, Nn);
  }
  hist_kernel<<<(E + 255) / 256, 256, 0, stream>>>(edst_in, E, cnt);
  scan_blocks_kernel<<<nscan, 1024, 0, stream>>>(cnt, Nn, rowoff, cursor, bsum);
  scan_add_kernel<<<nscan, 1024, 0, stream>>>(Nn, rowoff, cursor, bsum, nscan);
  scatter_kernel<<<(E + Nn + 255) / 256, 256, 0, stream>>>(esrc_in, edst_in, E, Nn, cursor, esrc);

  // layer 1: GEMM (fp8 h1 out) + fused attn1 logits, then agg1 (fp8 gather)
  {
    dim3 g(HC1 / 128, (Nn + 63) / 64);
    gemm1_fused_kernel<<<g, 256, 0, stream>>>(x, W1T, h1f8, a_src1, a_dst1,
                                              als1, ald1, Nn);
    int ablocks = (Nn + 3) / 4;
    agg1_kernel<<<ablocks, 256, 0, stream>>>(h1f8, (const float4*)als1, (const float4*)ald1,
                                             rowoff, esrc, b1, hact, Nn);
  }

  // layer 2: GEMM + fused attn2 logits, then agg2 (bf16 gather)
  {
    int blocks = (Nn + 127) / 128;
    gemm2_fused_kernel<<<blocks, 256, 0, stream>>>(hact, W2T, h2b, a_src2, a_dst2,
                                                   als2, ald2, Nn);
    int ablocks = (Nn + 3) / 4;
    agg2_kernel<<<ablocks, 256, 0, stream>>>(h2b, als2, ald2, rowoff, esrc, b2, out, Nn);
  }
}

// Round 14
// 240.843 us; speedup vs baseline: 1.1903x; 1.0133x over previous
//
#include <hip/hip_runtime.h>
#include <math.h>

#define F_IN 512
#define HC1 256   // HEADS*HID
#define HEADS 4
#define HID 64
#define NCLS 64
#define NEG_SLOPE 0.2f
#define EPS_DENOM 1e-16f

using short8 = __attribute__((ext_vector_type(8))) short;
using f32x4  = __attribute__((ext_vector_type(4))) float;

__device__ inline float wave_sum(float v) {
#pragma unroll
  for (int s = 32; s > 0; s >>= 1) v += __shfl_xor(v, s);
  return v;
}

__device__ inline unsigned short f2bf(float f) {
  unsigned int u = __float_as_uint(f);
  u = (u + 0x7FFF + ((u >> 16) & 1)) >> 16;   // RNE
  return (unsigned short)u;
}
__device__ inline float bflo(unsigned int u) { return __uint_as_float(u << 16); }
__device__ inline float bfhi(unsigned int u) { return __uint_as_float(u & 0xFFFF0000u); }

__device__ inline unsigned int cvtpk_bf16(float lo, float hi) {
  unsigned int r;
  asm("v_cvt_pk_bf16_f32 %0, %1, %2" : "=v"(r) : "v"(lo), "v"(hi));
  return r;
}

// ---- fp8 e4m3 (OCP) encode/decode ----
__device__ inline unsigned char f2fp8(float f) {
#if __has_builtin(__builtin_amdgcn_cvt_pk_fp8_f32)
  return (unsigned char)(__builtin_amdgcn_cvt_pk_fp8_f32(f, f, 0, false) & 0xFF);
#else
  unsigned u = __float_as_uint(f);
  unsigned s = (u >> 24) & 0x80;
  float af = fabsf(f);
  if (af > 448.f) return (unsigned char)(s | 0x7E);
  if (af < 0.0009765625f) return (unsigned char)s;
  if (af < 0.015625f) {             // denorm: m = round(af * 512)
    int m = (int)(af * 512.f + 0.5f);
    return (unsigned char)(s | m);
  }
  unsigned au = u & 0x7FFFFFFF;
  unsigned r = au + 0x0007FFFF + ((au >> 20) & 1);   // RNE at bit 20
  int e = (int)(r >> 23) - 120;
  int m = (r >> 20) & 7;
  if (e > 15) { e = 15; m = 6; }
  return (unsigned char)(s | (e << 3) | m);
#endif
}

template <bool HI>
__device__ inline void fp8x2_dec(unsigned int u, float& a, float& b) {
#if __has_builtin(__builtin_amdgcn_cvt_pk_f32_fp8)
  auto r = __builtin_amdgcn_cvt_pk_f32_fp8((int)u, HI);   // HI is a constant
  a = r[0]; b = r[1];
#else
  unsigned w = HI ? (u >> 16) : u;
  auto dec1 = [](unsigned v) -> float {
    unsigned sg = v >> 7, e = (v >> 3) & 15, m = v & 7;
    float mag = e ? __uint_as_float(((e + 120u) << 23) | (m << 20))
                  : (float)m * 0.001953125f;
    return sg ? -mag : mag;
  };
  a = dec1(w & 0xFF); b = dec1((w >> 8) & 0xFF);
#endif
}

__device__ inline void async_copy16(const void* g, void* l) {
  __builtin_amdgcn_global_load_lds((const __attribute__((address_space(1))) void*)g,
                                   (__attribute__((address_space(3))) void*)l, 16, 0, 0);
}

// ---------------- prep: W1T + W2T transpose-casts + cnt zeroing (one kernel) --------

__global__ void prep_kernel(const float* __restrict__ W1, unsigned short* __restrict__ W1T,
                            const float* __restrict__ W2, unsigned short* __restrict__ W2T,
                            int* __restrict__ cnt, int n) {
  const int n1 = F_IN * HC1;     // 131072
  const int n2 = HC1 * NCLS;     // 16384
  int id = blockIdx.x * blockDim.x + threadIdx.x;
  if (id < n1) {
    int nn = id / F_IN, k = id % F_IN;
    W1T[id] = f2bf(W1[(size_t)k * HC1 + nn]);
  } else if (id < n1 + n2) {
    int j = id - n1;
    int nn = j / HC1, k = j % HC1;
    W2T[j] = f2bf(W2[(size_t)k * NCLS + nn]);
  } else if (id < n1 + n2 + n) {
    cnt[id - n1 - n2] = 0;
  }
}

// ---------------- CSR build ----------------

__global__ void hist_kernel(const int* __restrict__ dst, int E, int* __restrict__ cnt) {
  int i = blockIdx.x * blockDim.x + threadIdx.x;
  int stride = gridDim.x * blockDim.x;
  for (int e = i; e < E; e += stride) atomicAdd(&cnt[dst[e]], 1);
}

__global__ void scan_blocks_kernel(const int* __restrict__ cnt, int n,
                                   int* __restrict__ rowoff, int* __restrict__ cursor,
                                   int* __restrict__ bsum) {
  __shared__ int wpart[16];
  int b = blockIdx.x, tid = threadIdx.x;
  int i = b * 1024 + tid;
  int lane = tid & 63, wid = tid >> 6;
  int v = (i < n) ? (cnt[i] + 1) : 0;   // +1 = self loop
  int x = v;
#pragma unroll
  for (int s = 1; s < 64; s <<= 1) {
    int t = __shfl_up(x, s);
    if (lane >= s) x += t;
  }
  if (lane == 63) wpart[wid] = x;
  __syncthreads();
  if (wid == 0) {
    int p = (lane < 16) ? wpart[lane] : 0;
#pragma unroll
    for (int s = 1; s < 16; s <<= 1) {
      int t = __shfl_up(p, s);
      if (lane >= s) p += t;
    }
    if (lane < 16) wpart[lane] = p;
  }
  __syncthreads();
  int incl = x + (wid ? wpart[wid - 1] : 0);
  if (i < n) { rowoff[i + 1] = incl; cursor[i] = incl - v; }
  if (tid == 1023) bsum[b] = incl;
  if (b == 0 && tid == 0) rowoff[0] = 0;
}

__global__ void scan_add_kernel(int n, int* __restrict__ rowoff, int* __restrict__ cursor,
                                const int* __restrict__ bsum, int nb) {
  __shared__ int sscan[64];
  int tid = threadIdx.x;
  if (tid < 64) {
    int v = (tid < nb) ? bsum[tid] : 0;
    int x = v;
#pragma unroll
    for (int s = 1; s < 64; s <<= 1) {
      int t = __shfl_up(x, s);
      if (tid >= s) x += t;
    }
    sscan[tid] = x;   // inclusive
  }
  __syncthreads();
  int off = blockIdx.x ? sscan[blockIdx.x - 1] : 0;
  int i = blockIdx.x * 1024 + tid;
  if (i < n) { rowoff[i + 1] += off; cursor[i] += off; }
}

__global__ void scatter_kernel(const int* __restrict__ src, const int* __restrict__ dst,
                               int E, int n, int* __restrict__ cursor, int* __restrict__ esrc) {
  int i = blockIdx.x * blockDim.x + threadIdx.x;
  int stride = gridDim.x * blockDim.x;
  for (int e = i; e < E + n; e += stride) {
    int s, d;
    if (e < E) { s = src[e]; d = dst[e]; } else { s = e - E; d = s; }
    int pos = atomicAdd(&cursor[d], 1);
    esrc[pos] = s;
  }
}

// ---------------- GEMM1: x(fp32)@W1 -> h1 fp8, fused attn1 dots ----------------
// R13 structure + both-sides XOR swizzle (rule #21): global SOURCE slot pre-swizzled,
// LDS dest linear (global_load_lds requirement), ds_read applies the same XOR.
// A rows = 128B (exact bank wrap -> was 16-way conflict): slot^(r&7) over 8x16B slots.
// B rows = 64B (was 8-way): slot^(r&3) over 4x16B slots.

__global__ __launch_bounds__(256)
void gemm1_fused_kernel(const float* __restrict__ A, const unsigned short* __restrict__ BT,
                        unsigned char* __restrict__ Cf8,
                        const float* __restrict__ as1, const float* __restrict__ ad1,
                        float* __restrict__ als, float* __restrict__ ald, int M) {
  constexpr int BM = 64, BN = 128, BK = 32, K = F_IN, Nn = HC1;
  __shared__ float          Af[2][BM * BK];    // 8KB each
  __shared__ unsigned short Bh[2][BN * BK];    // 8KB each  (32KB total)
  const int t = threadIdx.x;
  const int lane = t & 63;
  const int w = t >> 6;                        // 0..3
  const int wrow = (w >> 1) * 32;
  const int wcol = (w & 1) * 64;
  const int row0 = blockIdx.y * BM;
  const int col0 = blockIdx.x * BN;
  const int head = (col0 + wcol) >> 6;         // wave owns one full head (64 cols)
  const int lrow = lane & 15;
  const int lk = (lane >> 4) * 8;

  auto stageA = [&](int buf, int k0) {
#pragma unroll
    for (int i = 0; i < 2; ++i) {
      int c = i * 256 + t;                     // 512 chunks: row=c>>3, slot=c&7 (16B)
      int r = c >> 3, sl = c & 7;
      int grow = row0 + r; if (grow > M - 1) grow = M - 1;
      const float* g = A + (size_t)grow * K + k0 + ((sl ^ (r & 7)) << 2);
      async_copy16(g, (char*)&Af[buf][0] + (size_t)(i * 256 + w * 64) * 16);
    }
  };
  auto stageB = [&](int buf, int k0) {
#pragma unroll
    for (int i = 0; i < 2; ++i) {
      int c = i * 256 + t;                     // 512 chunks: row=c>>2, slot=c&3 (16B)
      int r = c >> 2, sl = c & 3;
      const unsigned short* g = BT + (size_t)(col0 + r) * K + k0 + ((sl ^ (r & 3)) << 3);
      async_copy16(g, (char*)&Bh[buf][0] + (size_t)(i * 256 + w * 64) * 16);
    }
  };

  f32x4 acc[2][4] = {};
  stageA(0, 0); stageB(0, 0);
  int cur = 0;
  for (int k0 = 0; k0 < K; k0 += BK) {
    __syncthreads();                           // buf[cur] staged
    if (k0 + BK < K) { stageA(cur ^ 1, k0 + BK); stageB(cur ^ 1, k0 + BK); }
    short8 a[2], b[4];
#pragma unroll
    for (int m = 0; m < 2; ++m) {
      int r = wrow + m * 16 + lrow;
      const float* rowp = &Af[cur][r * BK];
      int s0 = lk >> 2;                        // 16B-slot (0,2,4,6)
      float4 f0 = *(const float4*)(rowp + (((s0    ) ^ (r & 7)) << 2));
      float4 f1 = *(const float4*)(rowp + (((s0 | 1) ^ (r & 7)) << 2));
      union { short8 s; uint4 u; } pk;
      pk.u.x = cvtpk_bf16(f0.x, f0.y); pk.u.y = cvtpk_bf16(f0.z, f0.w);
      pk.u.z = cvtpk_bf16(f1.x, f1.y); pk.u.w = cvtpk_bf16(f1.z, f1.w);
      a[m] = pk.s;
    }
#pragma unroll
    for (int n = 0; n < 4; ++n) {
      int r = wcol + n * 16 + lrow;
      int s = lk >> 3;                         // 16B-slot (0..3)
      b[n] = *(const short8*)&Bh[cur][r * BK + ((s ^ (r & 3)) << 3)];
    }
#pragma unroll
    for (int m = 0; m < 2; ++m)
#pragma unroll
      for (int n = 0; n < 4; ++n)
        acc[m][n] = __builtin_amdgcn_mfma_f32_16x16x32_bf16(a[m], b[n], acc[m][n], 0, 0, 0);
    cur ^= 1;
  }

  // epilogue: fp8 C write + fused per-head attention dots (from f32 acc)
  float asv[4], adv[4];
#pragma unroll
  for (int n = 0; n < 4; ++n) {
    asv[n] = as1[head * 64 + n * 16 + lrow];
    adv[n] = ad1[head * 64 + n * 16 + lrow];
  }
#pragma unroll
  for (int m = 0; m < 2; ++m) {
#pragma unroll
    for (int j = 0; j < 4; ++j) {
      int r = row0 + wrow + m * 16 + (lane >> 4) * 4 + j;
      float ps = 0.f, pd = 0.f;
#pragma unroll
      for (int n = 0; n < 4; ++n) {
        float v = acc[m][n][j];
        ps += v * asv[n];
        pd += v * adv[n];
        if (r < M) Cf8[(size_t)r * Nn + col0 + wcol + n * 16 + lrow] = f2fp8(v);
      }
#pragma unroll
      for (int s = 1; s < 16; s <<= 1) {
        ps += __shfl_xor(ps, s);
        pd += __shfl_xor(pd, s);
      }
      if ((lane & 15) == 0 && r < M) {
        als[r * HEADS + head] = ps;
        ald[r * HEADS + head] = pd;
      }
    }
  }
}

// ---------------- GEMM2: hact(bf16)@W2 -> h2b(bf16), fused attn2 dots ----------

__global__ __launch_bounds__(256)
void gemm2_fused_kernel(const unsigned short* __restrict__ A,
                        const unsigned short* __restrict__ BT,
                        unsigned short* __restrict__ Cb,
                        const float* __restrict__ as2, const float* __restrict__ ad2,
                        float* __restrict__ als, float* __restrict__ ald, int M) {
  constexpr int BM = 128, BN = 64, BK = 32, K = HC1, Nn = NCLS;
  __shared__ unsigned short Alds[BM * BK];
  __shared__ unsigned short Blds[BN * BK];
  __shared__ float sps[BM], spd[BM];
  const int t = threadIdx.x;
  const int lane = t & 63;
  const int w = t >> 6;
  const int wr = (w >> 1) * 64;
  const int wc = (w & 1) * 32;
  const int row0 = blockIdx.x * BM;
  const int lrow = lane & 15;
  const int lk = (lane >> 4) * 8;
  if (t < BM) { sps[t] = 0.f; spd[t] = 0.f; }

  f32x4 acc[4][2] = {};
  for (int k0 = 0; k0 < K; k0 += BK) {
#pragma unroll
    for (int i = 0; i < 2; ++i) {
      int c = i * 256 + t;
      int arr = c >> 2;
      int ak = (c & 3) * 8;
      int grow = row0 + arr; if (grow > M - 1) grow = M - 1;
      const unsigned short* g = A + (size_t)grow * K + k0 + ak;
      unsigned short* l = Alds + (size_t)(i * 256 + w * 64) * 8;
      async_copy16(g, l);
    }
    {
      int c = t;
      int br = c >> 2;
      int bk = (c & 3) * 8;
      const unsigned short* g = BT + (size_t)br * K + k0 + bk;
      unsigned short* l = Blds + (size_t)(w * 64) * 8;
      async_copy16(g, l);
    }
    __syncthreads();
    short8 a[4], b[2];
#pragma unroll
    for (int m = 0; m < 4; ++m)
      a[m] = *(const short8*)&Alds[(wr + m * 16 + lrow) * BK + lk];
#pragma unroll
    for (int n = 0; n < 2; ++n)
      b[n] = *(const short8*)&Blds[(wc + n * 16 + lrow) * BK + lk];
#pragma unroll
    for (int m = 0; m < 4; ++m)
#pragma unroll
      for (int n = 0; n < 2; ++n)
        acc[m][n] = __builtin_amdgcn_mfma_f32_16x16x32_bf16(a[m], b[n], acc[m][n], 0, 0, 0);
    __syncthreads();
  }

  float asv[2], adv[2];
#pragma unroll
  for (int n = 0; n < 2; ++n) {
    asv[n] = as2[wc + n * 16 + lrow];
    adv[n] = ad2[wc + n * 16 + lrow];
  }
#pragma unroll
  for (int m = 0; m < 4; ++m) {
#pragma unroll
    for (int j = 0; j < 4; ++j) {
      int rl = wr + m * 16 + (lane >> 4) * 4 + j;
      int r = row0 + rl;
      float ps = 0.f, pd = 0.f;
#pragma unroll
      for (int n = 0; n < 2; ++n) {
        float v = acc[m][n][j];
        ps += v * asv[n];
        pd += v * adv[n];
        if (r < M) Cb[(size_t)r * Nn + wc + n * 16 + lrow] = f2bf(v);
      }
#pragma unroll
      for (int s = 1; s < 16; s <<= 1) {
        ps += __shfl_xor(ps, s);
        pd += __shfl_xor(pd, s);
      }
      if ((lane & 15) == 0) {
        atomicAdd(&sps[rl], ps);
        atomicAdd(&spd[rl], pd);
      }
    }
  }
  __syncthreads();
  if (t < BM) {
    int r = row0 + t;
    if (r < M) { als[r] = sps[t]; ald[r] = spd[t]; }
  }
}

// ---------------- aggregation ----------------
// agg1: fp8 feature gather (halved per-XCD L2 compulsory fill — R13 verified).

__global__ void agg1_kernel(const unsigned char* __restrict__ h1f8,
                            const float4* __restrict__ als1, const float4* __restrict__ ald1,
                            const int* __restrict__ rowoff, const int* __restrict__ esrc,
                            const float* __restrict__ b1, unsigned short* __restrict__ hact,
                            int n) {
  __shared__ float wlds[4][256];
  __shared__ int   slds[4][64];
  int w = threadIdx.x >> 6;
  int node = blockIdx.x * 4 + w;
  if (node >= n) return;
  int lane = threadIdx.x & 63;
  int hi = lane >> 5;        // which of the 2 edges covered by one instruction
  int cl = lane & 31;        // channels cl*8 .. cl*8+7
  int head = cl >> 3;
  int beg = rowoff[node], end = rowoff[node + 1];
  float4 aldn = ald1[node];
  f32x4 accA = {0.f, 0.f, 0.f, 0.f};
  f32x4 accB = {0.f, 0.f, 0.f, 0.f};
  float dl0 = 0.f, dl1 = 0.f, dl2 = 0.f, dl3 = 0.f;

  for (int base = beg; base < end; base += 64) {
    int cnt = min(64, end - base);
    if (lane < cnt) {
      int s = esrc[base + lane];
      float4 av = als1[s];
      float v, w0, w1, w2, w3;
      v = av.x + aldn.x; v = fmaxf(v, NEG_SLOPE * v); w0 = __expf(v);
      v = av.y + aldn.y; v = fmaxf(v, NEG_SLOPE * v); w1 = __expf(v);
      v = av.z + aldn.z; v = fmaxf(v, NEG_SLOPE * v); w2 = __expf(v);
      v = av.w + aldn.w; v = fmaxf(v, NEG_SLOPE * v); w3 = __expf(v);
      dl0 += w0; dl1 += w1; dl2 += w2; dl3 += w3;
      slds[w][lane] = s;
      float4 wv = {w0, w1, w2, w3};
      *(float4*)&wlds[w][lane * 4] = wv;
    }

    uint2 dA[4], dB[4];
    float wA[4], wB[4];
    auto ISSUE = [&](int j0, uint2* d, float* wj) {
#pragma unroll
      for (int ii = 0; ii < 4; ++ii) {
        int e = j0 + 2 * ii + hi;
        bool val = e < cnt;
        int se = val ? e : 0;
        int ss = slds[w][se];
        wj[ii] = val ? wlds[w][se * 4 + head] : 0.f;
        d[ii] = *(const uint2*)&h1f8[(size_t)ss * HC1 + cl * 8];
      }
    };
    auto CONSUME = [&](const uint2* d, const float* wj) {
#pragma unroll
      for (int ii = 0; ii < 4; ++ii) {
        float q = wj[ii];
        float a0, a1, a2, a3, b0, b1, b2, b3;
        fp8x2_dec<false>(d[ii].x, a0, a1);
        fp8x2_dec<true >(d[ii].x, a2, a3);
        fp8x2_dec<false>(d[ii].y, b0, b1);
        fp8x2_dec<true >(d[ii].y, b2, b3);
        accA[0] += q * a0; accA[1] += q * a1; accA[2] += q * a2; accA[3] += q * a3;
        accB[0] += q * b0; accB[1] += q * b1; accB[2] += q * b2; accB[3] += q * b3;
      }
    };

    ISSUE(0, dA, wA);
    for (int j0 = 8;; j0 += 16) {
      bool hasB = j0 < cnt;
      if (hasB) ISSUE(j0, dB, wB);
      CONSUME(dA, wA);
      if (!hasB) break;
      bool hasA = (j0 + 8) < cnt;
      if (hasA) ISSUE(j0 + 8, dA, wA);
      CONSUME(dB, wB);
      if (!hasA) break;
    }
  }

#pragma unroll
  for (int k = 0; k < 4; ++k) {
    accA[k] += __shfl_xor(accA[k], 32);
    accB[k] += __shfl_xor(accB[k], 32);
  }
  float d0 = wave_sum(dl0), d1 = wave_sum(dl1);
  float d2 = wave_sum(dl2), d3 = wave_sum(dl3);
  float den = head < 2 ? (head == 0 ? d0 : d1) : (head == 2 ? d2 : d3);
  float rden = 1.f / (den + EPS_DENOM);
  if (hi == 0) {
    float4 bv0 = *(const float4*)&b1[cl * 8];
    float4 bv1 = *(const float4*)&b1[cl * 8 + 4];
    float o[8];
    o[0] = accA[0] * rden + bv0.x; o[1] = accA[1] * rden + bv0.y;
    o[2] = accA[2] * rden + bv0.z; o[3] = accA[3] * rden + bv0.w;
    o[4] = accB[0] * rden + bv1.x; o[5] = accB[1] * rden + bv1.y;
    o[6] = accB[2] * rden + bv1.z; o[7] = accB[3] * rden + bv1.w;
    ushort4 ov0, ov1;
#pragma unroll
    for (int k = 0; k < 8; ++k) o[k] = o[k] > 0.f ? o[k] : __expf(o[k]) - 1.f;  // ELU
    ov0.x = f2bf(o[0]); ov0.y = f2bf(o[1]); ov0.z = f2bf(o[2]); ov0.w = f2bf(o[3]);
    ov1.x = f2bf(o[4]); ov1.y = f2bf(o[5]); ov1.z = f2bf(o[6]); ov1.w = f2bf(o[7]);
    *(ushort4*)&hact[(size_t)node * HC1 + cl * 8] = ov0;
    *(ushort4*)&hact[(size_t)node * HC1 + cl * 8 + 4] = ov1;
  }
}

__global__ void agg2_kernel(const unsigned short* __restrict__ h2b,
                            const float* __restrict__ als2, const float* __restrict__ ald2,
                            const int* __restrict__ rowoff, const int* __restrict__ esrc,
                            const float* __restrict__ b2, float* __restrict__ out, int n) {
  __shared__ float wlds[4][64];
  __shared__ int   slds[4][64];
  int w = threadIdx.x >> 6;
  int node = blockIdx.x * 4 + w;
  if (node >= n) return;
  int lane = threadIdx.x & 63;
  int eg = lane >> 3;
  int cl = lane & 7;
  int beg = rowoff[node], end = rowoff[node + 1];
  float aldn = ald2[node];
  f32x4 accA = {0.f, 0.f, 0.f, 0.f};
  f32x4 accB = {0.f, 0.f, 0.f, 0.f};
  float dl = 0.f;
  for (int base = beg; base < end; base += 64) {
    int cnt = min(64, end - base);
    if (lane < cnt) {
      int s = esrc[base + lane];
      float v = als2[s] + aldn;
      v = fmaxf(v, NEG_SLOPE * v);
      float wl = __expf(v);
      dl += wl;
      slds[w][lane] = s;
      wlds[w][lane] = wl;
    }
    for (int j0 = 0; j0 < cnt; j0 += 32) {
      uint4 d[4]; float wj[4];
#pragma unroll
      for (int ii = 0; ii < 4; ++ii) {
        int e = j0 + ii * 8 + eg;
        bool val = e < cnt;
        int se = val ? e : 0;
        int ss = slds[w][se];
        wj[ii] = val ? wlds[w][se] : 0.f;
        d[ii] = *(const uint4*)&h2b[(size_t)ss * NCLS + cl * 8];
      }
#pragma unroll
      for (int ii = 0; ii < 4; ++ii) {
        float q = wj[ii];
        accA[0] += q * bflo(d[ii].x); accA[1] += q * bfhi(d[ii].x);
        accA[2] += q * bflo(d[ii].y); accA[3] += q * bfhi(d[ii].y);
        accB[0] += q * bflo(d[ii].z); accB[1] += q * bfhi(d[ii].z);
        accB[2] += q * bflo(d[ii].w); accB[3] += q * bfhi(d[ii].w);
      }
    }
  }
#pragma unroll
  for (int s = 8; s < 64; s <<= 1) {
#pragma unroll
    for (int k = 0; k < 4; ++k) {
      accA[k] += __shfl_xor(accA[k], s);
      accB[k] += __shfl_xor(accB[k], s);
    }
  }
  float den = wave_sum(dl);
  float rden = 1.f / (den + EPS_DENOM);
  float4 bv0 = *(const float4*)&b2[cl * 8];
  float4 bv1 = *(const float4*)&b2[cl * 8 + 4];
  float o[8];
  o[0] = accA[0] * rden + bv0.x; o[1] = accA[1] * rden + bv0.y;
  o[2] = accA[2] * rden + bv0.z; o[3] = accA[3] * rden + bv0.w;
  o[4] = accB[0] * rden + bv1.x; o[5] = accB[1] * rden + bv1.y;
  o[6] = accB[2] * rden + bv1.z; o[7] = accB[3] * rden + bv1.w;
  float mx = o[0];
#pragma unroll
  for (int k = 1; k < 8; ++k) mx = fmaxf(mx, o[k]);
#pragma unroll
  for (int s = 1; s < 8; s <<= 1) mx = fmaxf(mx, __shfl_xor(mx, s));
  float sm = 0.f;
#pragma unroll
  for (int k = 0; k < 8; ++k) sm += __expf(o[k] - mx);
#pragma unroll
  for (int s = 1; s < 8; s <<= 1) sm += __shfl_xor(sm, s);
  float ls = mx + __logf(sm);
  if (lane < 8) {
    float4 q0 = {o[0] - ls, o[1] - ls, o[2] - ls, o[3] - ls};
    float4 q1 = {o[4] - ls, o[5] - ls, o[6] - ls, o[7] - ls};
    *(float4*)&out[(size_t)node * NCLS + cl * 8] = q0;
    *(float4*)&out[(size_t)node * NCLS + cl * 8 + 4] = q1;
  }
}

// ---------------- launch ----------------

extern "C" void kernel_launch(void* const* d_in, const int* in_sizes, int n_in,
                              void* d_out, int out_size, void* d_ws, size_t ws_size,
                              hipStream_t stream) {
  const float* x      = (const float*)d_in[0];
  const int*   eidx   = (const int*)d_in[1];
  const float* W1     = (const float*)d_in[2];
  const float* a_src1 = (const float*)d_in[3];
  const float* a_dst1 = (const float*)d_in[4];
  const float* b1     = (const float*)d_in[5];
  const float* W2     = (const float*)d_in[6];
  const float* a_src2 = (const float*)d_in[7];
  const float* a_dst2 = (const float*)d_in[8];
  const float* b2     = (const float*)d_in[9];
  float* out = (float*)d_out;

  const int Nn = in_sizes[0] / F_IN;   // 50000
  const int E  = in_sizes[1] / 2;      // 800000
  const int* esrc_in = eidx;
  const int* edst_in = eidx + E;

  char* ws = (char*)d_ws;
  size_t off = 0;
  auto alloc = [&](size_t bytes) -> void* {
    void* p = ws + off;
    off += (bytes + 255) & ~(size_t)255;
    return p;
  };
  unsigned char*  h1f8   = (unsigned char*)alloc((size_t)Nn * HC1);
  unsigned short* hact   = (unsigned short*)alloc((size_t)Nn * HC1 * sizeof(short));
  unsigned short* h2b    = (unsigned short*)alloc((size_t)Nn * NCLS * sizeof(short));
  unsigned short* W1T    = (unsigned short*)alloc((size_t)F_IN * HC1 * sizeof(short));
  unsigned short* W2T    = (unsigned short*)alloc((size_t)HC1 * NCLS * sizeof(short));
  float*          als1   = (float*)alloc((size_t)Nn * HEADS * sizeof(float));
  float*          ald1   = (float*)alloc((size_t)Nn * HEADS * sizeof(float));
  float*          als2   = (float*)alloc((size_t)Nn * sizeof(float));
  float*          ald2   = (float*)alloc((size_t)Nn * sizeof(float));
  int*            cnt    = (int*)alloc((size_t)Nn * sizeof(int));
  int*            rowoff = (int*)alloc((size_t)(Nn + 1) * sizeof(int));
  int*            cursor = (int*)alloc((size_t)Nn * sizeof(int));
  int*            bsum   = (int*)alloc(256 * sizeof(int));
  int*            esrc   = (int*)alloc((size_t)(E + Nn) * sizeof(int));

  const int nscan = (Nn + 1023) / 1024;   // 49 (<=64)

  {
    int total = F_IN * HC1 + HC1 * NCLS + Nn;
    prep_kernel<<<(total + 255) / 256, 256, 0, stream>>>(W1, W1T, W2, W2T, cnt, Nn);
  }
  hist_kernel<<<(E + 255) / 256, 256, 0, stream>>>(edst_in, E, cnt);
  scan_blocks_kernel<<<nscan, 1024, 0, stream>>>(cnt, Nn, rowoff, cursor, bsum);
  scan_add_kernel<<<nscan, 1024, 0, stream>>>(Nn, rowoff, cursor, bsum, nscan);
  scatter_kernel<<<(E + Nn + 255) / 256, 256, 0, stream>>>(esrc_in, edst_in, E, Nn, cursor, esrc);

  // layer 1: GEMM (fp8 h1 out, swizzled LDS) + fused attn1 logits, then agg1
  {
    dim3 g(HC1 / 128, (Nn + 63) / 64);
    gemm1_fused_kernel<<<g, 256, 0, stream>>>(x, W1T, h1f8, a_src1, a_dst1,
                                              als1, ald1, Nn);
    int ablocks = (Nn + 3) / 4;
    agg1_kernel<<<ablocks, 256, 0, stream>>>(h1f8, (const float4*)als1, (const float4*)ald1,
                                             rowoff, esrc, b1, hact, Nn);
  }

  // layer 2: GEMM + fused attn2 logits, then agg2 (bf16 gather)
  {
    int blocks = (Nn + 127) / 128;
    gemm2_fused_kernel<<<blocks, 256, 0, stream>>>(hact, W2T, h2b, a_src2, a_dst2,
                                                   als2, ald2, Nn);
    int ablocks = (Nn + 3) / 4;
    agg2_kernel<<<ablocks, 256, 0, stream>>>(h2b, als2, ald2, rowoff, esrc, b2, out, Nn);
  }
}